// Round 1
// baseline (191.564 us; speedup 1.0000x reference)
//
#include <hip/hip_runtime.h>
#include <math.h>
#include <float.h>

#define NROWS 8192
#define NCOLS 32000
#define BLOCK 256
#define NVEC  (NCOLS / 4)   // 8000 float4 per row

// ---------------------------------------------------------------------------
// Kernel 1: one block per row. Single-pass online softmax (running max m,
// running sum s of exp(x - m)), then logpt = x_t - m - log(s), focal loss.
// ---------------------------------------------------------------------------
__global__ __launch_bounds__(BLOCK) void focal_row_kernel(
    const float* __restrict__ logits,
    const int*   __restrict__ target,
    float*       __restrict__ row_loss)
{
    const int row = blockIdx.x;
    const float4* rowp = reinterpret_cast<const float4*>(logits + (size_t)row * NCOLS);

    float m = -FLT_MAX;
    float s = 0.0f;

    // Strided, coalesced float4 sweep over this row.
    for (int j = threadIdx.x; j < NVEC; j += BLOCK) {
        float4 v = rowp[j];
        float mv = fmaxf(fmaxf(v.x, v.y), fmaxf(v.z, v.w));
        float nm = fmaxf(m, mv);
        s = s * __expf(m - nm)
          + __expf(v.x - nm) + __expf(v.y - nm)
          + __expf(v.z - nm) + __expf(v.w - nm);
        m = nm;
    }

    // Wave-level (64-lane) combine of (m, s).
    #pragma unroll
    for (int off = 1; off < 64; off <<= 1) {
        float om = __shfl_xor(m, off);
        float os = __shfl_xor(s, off);
        float nm = fmaxf(m, om);
        s = s * __expf(m - nm) + os * __expf(om - nm);
        m = nm;
    }

    // Cross-wave combine via LDS (BLOCK/64 = 4 waves).
    __shared__ float sm_m[BLOCK / 64];
    __shared__ float sm_s[BLOCK / 64];
    const int wave = threadIdx.x >> 6;
    const int lane = threadIdx.x & 63;
    if (lane == 0) { sm_m[wave] = m; sm_s[wave] = s; }
    __syncthreads();

    if (threadIdx.x == 0) {
        float M = sm_m[0];
        float S = sm_s[0];
        #pragma unroll
        for (int w = 1; w < BLOCK / 64; ++w) {
            float om = sm_m[w];
            float os = sm_s[w];
            float nm = fmaxf(M, om);
            S = S * __expf(M - nm) + os * __expf(om - nm);
            M = nm;
        }

        const int t = target[row];
        const float xt = logits[(size_t)row * NCOLS + t];
        const float logpt = xt - M - __logf(S);
        const float pt = __expf(logpt);

        // gamma: pt>=0.5 -> 0 ; pt<0.2 -> 5 ; else -> 3
        const float omp = 1.0f - pt;
        float w;
        if (pt >= 0.5f) {
            w = 1.0f;                         // (1-pt)^0
        } else if (pt < 0.2f) {
            float p2 = omp * omp;
            w = p2 * p2 * omp;                // (1-pt)^5
        } else {
            w = omp * omp * omp;              // (1-pt)^3
        }
        row_loss[row] = -w * logpt;
    }
}

// ---------------------------------------------------------------------------
// Kernel 2: reduce 8192 row losses -> mean (single block).
// ---------------------------------------------------------------------------
__global__ __launch_bounds__(BLOCK) void focal_reduce_kernel(
    const float* __restrict__ row_loss,
    float*       __restrict__ out)
{
    float acc = 0.0f;
    for (int i = threadIdx.x; i < NROWS; i += BLOCK) acc += row_loss[i];

    #pragma unroll
    for (int off = 1; off < 64; off <<= 1) acc += __shfl_xor(acc, off);

    __shared__ float sm[BLOCK / 64];
    const int wave = threadIdx.x >> 6;
    const int lane = threadIdx.x & 63;
    if (lane == 0) sm[wave] = acc;
    __syncthreads();

    if (threadIdx.x == 0) {
        float total = 0.0f;
        #pragma unroll
        for (int w = 0; w < BLOCK / 64; ++w) total += sm[w];
        out[0] = total * (1.0f / (float)NROWS);
    }
}

extern "C" void kernel_launch(void* const* d_in, const int* in_sizes, int n_in,
                              void* d_out, int out_size, void* d_ws, size_t ws_size,
                              hipStream_t stream)
{
    const float* logits = (const float*)d_in[0];
    const int*   target = (const int*)d_in[1];
    float* out = (float*)d_out;
    float* row_loss = (float*)d_ws;   // NROWS floats of scratch

    focal_row_kernel<<<NROWS, BLOCK, 0, stream>>>(logits, target, row_loss);
    focal_reduce_kernel<<<1, BLOCK, 0, stream>>>(row_loss, out);
}